// Round 5
// baseline (2679.148 us; speedup 1.0000x reference)
//
#include <hip/hip_runtime.h>
#include <stdint.h>

#define BB 8
#define NN 65536
#define GG 512
#define MM 64
#define STEPS 63            // GROUP_SIZE - 1
#define NWALK (BB*GG)       // 4096

#define FPT 256             // threads per FPS block = 4 waves (1 per SIMD)
#define FPK 16              // FPS blocks per batch
#define WPB (FPT/64)        // 4 waves per block
#define WVB (FPK*WPB)       // 64 waves per batch == wave width (poll = 1 load)
#define PPT (NN/(FPK*FPT))  // 16 points per thread
#define FPS_BLOCKS (BB*FPK) // 128

typedef unsigned long long ull;

// ---------------- threefry2x32 (JAX-exact, 20 rounds) ----------------
__device__ __forceinline__ uint32_t rotl32(uint32_t x, uint32_t r){ return (x<<r)|(x>>(32u-r)); }

__device__ __forceinline__ void tf2x32(uint32_t k0, uint32_t k1, uint32_t x0, uint32_t x1,
                                       uint32_t &o0, uint32_t &o1){
  const uint32_t ks2 = k0 ^ k1 ^ 0x1BD11BDAu;
  x0 += k0; x1 += k1;
#define TFR(r) { x0 += x1; x1 = rotl32(x1,(r)); x1 ^= x0; }
  TFR(13) TFR(15) TFR(26) TFR(6)
  x0 += k1;  x1 += ks2 + 1u;
  TFR(17) TFR(29) TFR(16) TFR(24)
  x0 += ks2; x1 += k0 + 2u;
  TFR(13) TFR(15) TFR(26) TFR(6)
  x0 += k0;  x1 += k1 + 3u;
  TFR(17) TFR(29) TFR(16) TFR(24)
  x0 += k1;  x1 += ks2 + 4u;
  TFR(13) TFR(15) TFR(26) TFR(6)
  x0 += ks2; x1 += k0 + 5u;
#undef TFR
  o0 = x0; o1 = x1;
}

// ---------------- kernel A: PRNG table + slot/center init ----------------
__global__ void rng_init_kernel(uint4* __restrict__ rng,
                                ull* __restrict__ slots,
                                int* __restrict__ center_idx){
  int tid = blockIdx.x*blockDim.x + threadIdx.x;
  if (tid < 2*BB*WVB) slots[tid] = 0ull;          // tagged ping-pong slots (tag 0 = idle)
  if (tid < BB) center_idx[tid*GG] = 0;           // FPS start index = 0
  if (tid >= STEPS*NWALK) return;
  int step = tid / NWALK;
  int walk = tid - step*NWALK;
  uint32_t kj0,kj1,t0,t1,a0,a1,b0,b1,p0,p1,q0,q1,r0,r1,l0,l1;
  tf2x32(0u, 42u, 0u, (uint32_t)walk, kj0, kj1);  // key_j = TF(master(0,42), (0,j))
  tf2x32(kj0, kj1, 0u, (uint32_t)step, t0, t1);   // step key
  tf2x32(t0, t1, 0u, 0u, a0, a1);                 // ka
  tf2x32(t0, t1, 0u, 1u, b0, b1);                 // kb
  tf2x32(a0, a1, 0u, 0u, p0, p1);                 // uniform bits x3
  tf2x32(a0, a1, 0u, 1u, q0, q1);
  tf2x32(a0, a1, 0u, 2u, r0, r1);
  tf2x32(b0, b1, 0u, 1u, l0, l1);                 // randint lower bits
  uint4 e;
  e.x = ((p0 ^ p1) >> 9) | 0x3f800000u;
  e.y = ((q0 ^ q1) >> 9) | 0x3f800000u;
  e.z = ((r0 ^ r1) >> 9) | 0x3f800000u;
  e.w = (l0 ^ l1) & 0xFFFFu;
  rng[tid] = e;
}

// ---------------- kernel B: farthest point sampling, flat wave-level sync ----------------
// 8 batches x 16 blocks x 256 threads (4 waves, 1/SIMD). 64 waves per batch.
// NO __syncthreads in the loop: each wave butterflies its own max, lane 0
// stores it to slot[wave_id] (tag=it, ping-pong WAR-safe), then the wave
// polls all 64 slots (lane j <-> slot j, one coalesced 512B load/round),
// prefetches its slot's candidate coords during the straggler wait, and
// shfl-broadcasts the winner's coords after a 6-round butterfly + ballot.
// Slot u64 = dist_bits<<32 | (65535-idx)<<16 | it_tag; per-wave candidate
// index sets are disjoint -> slot values distinct -> unique ballot winner.
__global__ __launch_bounds__(FPT) void fps_kernel(const float* __restrict__ xyz,
                                                  ull* __restrict__ slots,
                                                  int* __restrict__ center_idx){
  const int b = blockIdx.x & 7;       // batch
  const int kblk = blockIdx.x >> 3;   // block shard 0..15
  const int t = threadIdx.x;
  const int lane = t & 63;
  const int wid = kblk*WPB + (t >> 6);        // wave id within batch: 0..63
  const float* bx = xyz + (size_t)b*NN*3;
  float px[PPT], py[PPT], pz[PPT], dd[PPT];
  const int base = kblk*(FPT*PPT);
#pragma unroll
  for(int q=0;q<PPT;q++){
    int gi = base + q*FPT + t;
    px[q]=bx[3*gi]; py[q]=bx[3*gi+1]; pz[q]=bx[3*gi+2];
    dd[q]=1e10f;
  }
  float cx = bx[0], cy = bx[1], cz = bx[2];   // start center = index 0
  for(int it=1; it<GG; ++it){
    // per-thread scan (ascending gi + strict '>' keeps lowest idx on ties)
    float bd = -1.0f; int bgi = 0;
#pragma unroll
    for(int q=0;q<PPT;q++){
      // match XLA: uncontracted mul/add, sum order ((dx^2+dy^2)+dz^2)
      float dx = __fadd_rn(px[q], -cx);
      float dy = __fadd_rn(py[q], -cy);
      float dz = __fadd_rn(pz[q], -cz);
      float d  = __fmul_rn(dx,dx);
      d = __fadd_rn(d, __fmul_rn(dy,dy));
      d = __fadd_rn(d, __fmul_rn(dz,dz));
      float nd = fminf(dd[q], d);
      dd[q] = nd;
      int gi = base + q*FPT + t;
      if (nd > bd){ bd = nd; bgi = gi; }
    }
    ull best = ((ull)__float_as_uint(bd) << 32) | ((ull)(unsigned)(65535 - bgi) << 16);
#pragma unroll
    for(int off=32; off; off>>=1){
      ull o = __shfl_xor(best, off, 64);
      best = o > best ? o : best;               // wave max (all lanes)
    }
    ull* sl = slots + (((size_t)(it & 1))*BB + b)*WVB;
    if (lane==0)
      __hip_atomic_store(&sl[wid], best | (unsigned)it, __ATOMIC_RELAXED, __HIP_MEMORY_SCOPE_AGENT);
    // poll: lane j polls slot j (coalesced 512B across the wave)
    ull v;
    do { v = __hip_atomic_load(&sl[lane], __ATOMIC_RELAXED, __HIP_MEMORY_SCOPE_AGENT); }
    while ((v & 0xFFFFull) != (ull)(unsigned)it);
    // prefetch this slot's candidate coords while stragglers arrive
    unsigned int idxj = 65535u - (unsigned)((v >> 16) & 0xFFFFu);
    float pcx = bx[3*idxj], pcy = bx[3*idxj+1], pcz = bx[3*idxj+2];
    ull m = v;
#pragma unroll
    for(int off=32; off; off>>=1){
      ull o = __shfl_xor(m, off, 64);
      m = o > m ? o : m;                        // max over the 64 slots
    }
    ull bal = __ballot(v == m);                 // winner slot unique
    int wl = (int)(__ffsll(bal) - 1);
    cx = __shfl(pcx, wl, 64);
    cy = __shfl(pcy, wl, 64);
    cz = __shfl(pcz, wl, 64);
    if (wid==0 && lane==0){
      unsigned int widx = 65535u - (unsigned)((m >> 16) & 0xFFFFu);
      __hip_atomic_store(&center_idx[b*GG + it], (int)widx, __ATOMIC_RELAXED, __HIP_MEMORY_SCOPE_AGENT);
    }
  }
}

// ---------------- kernel C: random walks + gather, software-pipelined ----------------
// One thread per walk. Chain per step = hash probes + pick + row select;
// ring rows of all 3 candidates prefetched one step ahead (off-chain).
#define WBLK 64
__global__ __launch_bounds__(WBLK) void walk_kernel(const float* __restrict__ xyz,
                                                    const int* __restrict__ ring,
                                                    const uint4* __restrict__ rng,
                                                    const int* __restrict__ center_idx,
                                                    float* __restrict__ out){
  __shared__ uint32_t hashv[128*WBLK];            // [slot][thread], private columns (conflict-free)
  const int t = threadIdx.x;
  for(int i=0;i<128;i++) hashv[i*WBLK + t] = 0u;

  const int walk = blockIdx.x*WBLK + t;
  const int b = walk >> 9;
  const float* bx = xyz + (size_t)b*NN*3;
  const int*  br = ring + (size_t)b*NN*3;

  float* out_nb = out;                            // [NWALK][64][3]
  float* out_c  = out + (size_t)NWALK*MM*3;       // [NWALK][3]
  float* out_i  = out_c + (size_t)NWALK*3;        // [NWALK][64] (idx as float)

  const int cidx = center_idx[walk];
  const float cx = bx[3*cidx], cy = bx[3*cidx+1], cz = bx[3*cidx+2];
  out_c[walk*3+0]=cx; out_c[walk*3+1]=cy; out_c[walk*3+2]=cz;
  out_i[(size_t)walk*MM] = (float)cidx;
  { size_t o = (size_t)walk*MM*3; out_nb[o]=0.0f; out_nb[o+1]=0.0f; out_nb[o+2]=0.0f; }

  auto H = [](uint32_t v)->uint32_t { return (v*2654435761u) >> 25; };
  auto slow_has = [&](uint32_t v, uint32_t h)->bool{      // h = first probe (already checked)
    for(;;){ h=(h+1u)&127u; uint32_t c = hashv[h*WBLK+t];
             if (c==0u) return false;
             if (c==v+1u) return true; }
  };
  auto ins = [&](uint32_t v){
    uint32_t h = H(v);
    for(;;){ uint32_t c = hashv[h*WBLK+t];
             if (c==v+1u) return;
             if (c==0u){ hashv[h*WBLK+t]=v+1u; return; }
             h=(h+1u)&127u; }
  };

  ins((uint32_t)cidx);
  int n0 = br[3*cidx], n1 = br[3*cidx+1], n2 = br[3*cidx+2];
  int r00=br[3*n0], r01=br[3*n0+1], r02=br[3*n0+2];
  int r10=br[3*n1], r11=br[3*n1+1], r12=br[3*n1+2];
  int r20=br[3*n2], r21=br[3*n2+1], r22=br[3*n2+2];
  uint4 e = rng[walk];

  for(int i=0;i<STEPS;i++){
    uint4 en = (i < STEPS-1) ? rng[(size_t)(i+1)*NWALK + walk] : e;  // prefetch next rng
    uint32_t h0=H((uint32_t)n0), h1=H((uint32_t)n1), h2=H((uint32_t)n2);
    uint32_t c0=hashv[h0*WBLK+t], c1=hashv[h1*WBLK+t], c2=hashv[h2*WBLK+t];
    bool v0 = (c0!=0u) && ((c0==(uint32_t)n0+1u) || slow_has((uint32_t)n0,h0));
    bool v1 = (c1!=0u) && ((c1==(uint32_t)n1+1u) || slow_has((uint32_t)n1,h1));
    bool v2 = (c2!=0u) && ((c2==(uint32_t)n2+1u) || slow_has((uint32_t)n2,h2));
    bool m0=!v0, m1=!v1, m2=!v2;
    float s0 = m0 ? __fadd_rn(__uint_as_float(e.x), -1.0f) : -1.0f;
    float s1 = m1 ? __fadd_rn(__uint_as_float(e.y), -1.0f) : -1.0f;
    float s2 = m2 ? __fadd_rn(__uint_as_float(e.z), -1.0f) : -1.0f;
    int s = 0; float sb = s0;                     // first-max-wins argmax slot
    if (s1 > sb){ sb=s1; s=1; }
    if (s2 > sb){ sb=s2; s=2; }
    bool any = m0|m1|m2;
    int pick = s==0 ? n0 : (s==1 ? n1 : n2);
    int nxt  = any ? pick : (int)e.w;
    if (any){
      uint32_t cs = s==0?c0:(s==1?c1:c2);
      uint32_t hs = s==0?h0:(s==1?h1:h2);
      if (cs==0u) hashv[hs*WBLK+t] = (uint32_t)nxt + 1u;
      else ins((uint32_t)nxt);                    // collision chain (rare)
    } else {
      ins((uint32_t)nxt);                         // random jump (rare)
    }
    out_i[(size_t)walk*MM + i+1] = (float)nxt;
    float gx=bx[3*nxt], gy=bx[3*nxt+1], gz=bx[3*nxt+2];
    int nn0, nn1, nn2;
    if (any){
      nn0 = s==0?r00:(s==1?r10:r20);
      nn1 = s==0?r01:(s==1?r11:r21);
      nn2 = s==0?r02:(s==1?r12:r22);
    } else {
      nn0 = br[3*nxt]; nn1 = br[3*nxt+1]; nn2 = br[3*nxt+2];   // rare stall
    }
    n0=nn0; n1=nn1; n2=nn2;
    r00=br[3*n0]; r01=br[3*n0+1]; r02=br[3*n0+2];
    r10=br[3*n1]; r11=br[3*n1+1]; r12=br[3*n1+2];
    r20=br[3*n2]; r21=br[3*n2+1]; r22=br[3*n2+2];
    size_t o = ((size_t)walk*MM + (size_t)(i+1))*3;
    out_nb[o]   = __fadd_rn(gx, -cx);
    out_nb[o+1] = __fadd_rn(gy, -cy);
    out_nb[o+2] = __fadd_rn(gz, -cz);
    e = en;
  }
}

// ---------------- launcher ----------------
extern "C" void kernel_launch(void* const* d_in, const int* in_sizes, int n_in,
                              void* d_out, int out_size, void* d_ws, size_t ws_size,
                              hipStream_t stream) {
  const float* xyz  = (const float*)d_in[0];
  const int*   ring = (const int*)d_in[1];

  // workspace layout
  ull*   slots      = (ull*)d_ws;                                 // 2*8*64*8 = 8192 B
  int*   center_idx = (int*)((char*)d_ws + 8192);                 // 4096*4 B
  uint4* rng        = (uint4*)((char*)d_ws + 8192 + 16384);       // 258048*16 B
  float* out        = (float*)d_out;

  hipLaunchKernelGGL(rng_init_kernel, dim3((STEPS*NWALK)/256), dim3(256), 0, stream,
                     rng, slots, center_idx);
  hipLaunchKernelGGL(fps_kernel, dim3(FPS_BLOCKS), dim3(FPT), 0, stream,
                     xyz, slots, center_idx);
  hipLaunchKernelGGL(walk_kernel, dim3(NWALK/WBLK), dim3(WBLK), 0, stream,
                     xyz, ring, rng, center_idx, out);
}

// Round 6
// 1419.310 us; speedup vs baseline: 1.8876x; 1.8876x over previous
//
#include <hip/hip_runtime.h>
#include <stdint.h>

#define BB 8
#define NN 65536
#define GG 512
#define MM 64
#define STEPS 63            // GROUP_SIZE - 1
#define NWALK (BB*GG)       // 4096

#define FPT 256             // threads per FPS block = 4 waves (1 per SIMD)
#define FPK 16              // FPS blocks per batch
#define WPB (FPT/64)        // 4 waves per block
#define SPB (FPK*WPB)       // 64 slots per batch (one per wave) == wave width
#define PPT (NN/(FPK*FPT))  // 16 points per thread
#define FPS_BLOCKS (BB*FPK) // 128

typedef unsigned long long ull;

// ---------------- threefry2x32 (JAX-exact, 20 rounds) ----------------
__device__ __forceinline__ uint32_t rotl32(uint32_t x, uint32_t r){ return (x<<r)|(x>>(32u-r)); }

__device__ __forceinline__ void tf2x32(uint32_t k0, uint32_t k1, uint32_t x0, uint32_t x1,
                                       uint32_t &o0, uint32_t &o1){
  const uint32_t ks2 = k0 ^ k1 ^ 0x1BD11BDAu;
  x0 += k0; x1 += k1;
#define TFR(r) { x0 += x1; x1 = rotl32(x1,(r)); x1 ^= x0; }
  TFR(13) TFR(15) TFR(26) TFR(6)
  x0 += k1;  x1 += ks2 + 1u;
  TFR(17) TFR(29) TFR(16) TFR(24)
  x0 += ks2; x1 += k0 + 2u;
  TFR(13) TFR(15) TFR(26) TFR(6)
  x0 += k0;  x1 += k1 + 3u;
  TFR(17) TFR(29) TFR(16) TFR(24)
  x0 += k1;  x1 += ks2 + 4u;
  TFR(13) TFR(15) TFR(26) TFR(6)
  x0 += ks2; x1 += k0 + 5u;
#undef TFR
  o0 = x0; o1 = x1;
}

// ---------------- kernel A: PRNG table + slot/center init ----------------
__global__ void rng_init_kernel(uint4* __restrict__ rng,
                                ull* __restrict__ slots,
                                int* __restrict__ center_idx){
  int tid = blockIdx.x*blockDim.x + threadIdx.x;
  if (tid < 2*BB*SPB) slots[tid] = 0ull;          // tagged ping-pong slots (tag 0 = idle)
  if (tid < BB) center_idx[tid*GG] = 0;           // FPS start index = 0
  if (tid >= STEPS*NWALK) return;
  int step = tid / NWALK;
  int walk = tid - step*NWALK;
  uint32_t kj0,kj1,t0,t1,a0,a1,b0,b1,p0,p1,q0,q1,r0,r1,l0,l1;
  tf2x32(0u, 42u, 0u, (uint32_t)walk, kj0, kj1);  // key_j = TF(master(0,42), (0,j))
  tf2x32(kj0, kj1, 0u, (uint32_t)step, t0, t1);   // step key
  tf2x32(t0, t1, 0u, 0u, a0, a1);                 // ka
  tf2x32(t0, t1, 0u, 1u, b0, b1);                 // kb
  tf2x32(a0, a1, 0u, 0u, p0, p1);                 // uniform bits x3
  tf2x32(a0, a1, 0u, 1u, q0, q1);
  tf2x32(a0, a1, 0u, 2u, r0, r1);
  tf2x32(b0, b1, 0u, 1u, l0, l1);                 // randint lower bits
  uint4 e;
  e.x = ((p0 ^ p1) >> 9) | 0x3f800000u;
  e.y = ((q0 ^ q1) >> 9) | 0x3f800000u;
  e.z = ((r0 ^ r1) >> 9) | 0x3f800000u;
  e.w = (l0 ^ l1) & 0xFFFFu;
  rng[tid] = e;
}

// ---------------- kernel B: farthest point sampling ----------------
// 8 batches x 16 blocks x 256 threads (4 waves, 1/SIMD). 64 waves per batch,
// each owning a disjoint shard. Per iteration:
//   - every wave: scan PPT points, 6-round shfl butterfly, lane0 stores the
//     wave max DIRECTLY to slot[wid] (no barrier/LDS before the store);
//   - wave 0 only: polls all 64 slots (lane j <-> slot j, one coalesced 512B
//     load per pass); as each lane's slot arrives it immediately issues the
//     xyz gather of that slot's candidate (early-gather inside the loop);
//     butterfly over the 64 slot values + ballot -> winner lane; shfl coords;
//     writes winner coords to double-buffered LDS bc[it&1];
//   - ONE __syncthreads, then all waves read bc[it&1].
// Slot u64 = dist_bits<<32 | (65535-idx)<<16 | it_tag; ping-pong [2][BB][SPB]
// (WAR-safe: a wave reaches it+2 only after wave0 of its block observed all
// slots@it+1, which requires every wave's store@it+1, which follows their
// barrier@it). Only 16 polling waves per batch (R2's proven contention level).
__global__ __launch_bounds__(FPT) void fps_kernel(const float* __restrict__ xyz,
                                                  ull* __restrict__ slots,
                                                  int* __restrict__ center_idx){
  const int b = blockIdx.x & 7;       // batch (blocks of a batch land on one XCD under %8 round-robin)
  const int kblk = blockIdx.x >> 3;   // block shard 0..15
  const int t = threadIdx.x;
  const int lane = t & 63;
  const int w = t >> 6;               // wave in block 0..3
  const int wid = kblk*WPB + w;       // wave id in batch 0..63
  const float* bx = xyz + (size_t)b*NN*3;
  float px[PPT], py[PPT], pz[PPT], dd[PPT];
  const int base = kblk*(FPT*PPT);
#pragma unroll
  for(int q=0;q<PPT;q++){
    int gi = base + q*FPT + t;
    px[q]=bx[3*gi]; py[q]=bx[3*gi+1]; pz[q]=bx[3*gi+2];
    dd[q]=1e10f;
  }
  __shared__ float bc[2][3];          // double-buffered winner-coords broadcast
  float cx = bx[0], cy = bx[1], cz = bx[2];   // start center = index 0
  for(int it=1; it<GG; ++it){
    // per-thread scan (ascending gi + strict '>' keeps lowest idx on ties)
    float bd = -1.0f; int bgi = 0;
#pragma unroll
    for(int q=0;q<PPT;q++){
      // match XLA: uncontracted mul/add, sum order ((dx^2+dy^2)+dz^2)
      float dx = __fadd_rn(px[q], -cx);
      float dy = __fadd_rn(py[q], -cy);
      float dz = __fadd_rn(pz[q], -cz);
      float d  = __fmul_rn(dx,dx);
      d = __fadd_rn(d, __fmul_rn(dy,dy));
      d = __fadd_rn(d, __fmul_rn(dz,dz));
      float nd = fminf(dd[q], d);
      dd[q] = nd;
      int gi = base + q*FPT + t;
      if (nd > bd){ bd = nd; bgi = gi; }
    }
    ull best = ((ull)__float_as_uint(bd) << 32) | ((ull)(unsigned)(65535 - bgi) << 16);
#pragma unroll
    for(int off=32; off; off>>=1){
      ull o = __shfl_xor(best, off, 64);
      best = o > best ? o : best;               // wave max (all lanes)
    }
    ull* sl = slots + (((size_t)(it & 1))*BB + b)*SPB;
    if (lane==0)
      __hip_atomic_store(&sl[wid], best | (unsigned)it, __ATOMIC_RELAXED, __HIP_MEMORY_SCOPE_AGENT);
    if (w==0){
      // poll all 64 slots; early-gather each candidate's coords on arrival
      ull v; bool got = false;
      float pcx = 0.f, pcy = 0.f, pcz = 0.f;
      for(;;){
        v = __hip_atomic_load(&sl[lane], __ATOMIC_RELAXED, __HIP_MEMORY_SCOPE_AGENT);
        bool arr = ((v & 0xFFFFull) == (ull)(unsigned)it);
        if (arr && !got){
          unsigned int idxj = 65535u - (unsigned)((v >> 16) & 0xFFFFu);
          pcx = bx[3*idxj]; pcy = bx[3*idxj+1]; pcz = bx[3*idxj+2];
          got = true;
        }
        if (__all(arr)) break;
      }
      ull m = v;
#pragma unroll
      for(int off=32; off; off>>=1){
        ull o = __shfl_xor(m, off, 64);
        m = o > m ? o : m;                      // max over the 64 slots
      }
      ull bal = __ballot(v == m);               // winner slot unique (disjoint shards)
      int wl = (int)(__ffsll(bal) - 1);
      float wcx = __shfl(pcx, wl, 64);
      float wcy = __shfl(pcy, wl, 64);
      float wcz = __shfl(pcz, wl, 64);
      if (lane==0){
        bc[it&1][0]=wcx; bc[it&1][1]=wcy; bc[it&1][2]=wcz;
        if (kblk==0){
          unsigned int widx = 65535u - (unsigned)((m >> 16) & 0xFFFFu);
          __hip_atomic_store(&center_idx[b*GG + it], (int)widx, __ATOMIC_RELAXED, __HIP_MEMORY_SCOPE_AGENT);
        }
      }
    }
    __syncthreads();
    cx = bc[it&1][0]; cy = bc[it&1][1]; cz = bc[it&1][2];
  }
}

// ---------------- kernel C: random walks + gather, software-pipelined ----------------
// One thread per walk. Chain per step = hash probes + pick + row select;
// ring rows of all 3 candidates prefetched one step ahead (off-chain).
#define WBLK 64
__global__ __launch_bounds__(WBLK) void walk_kernel(const float* __restrict__ xyz,
                                                    const int* __restrict__ ring,
                                                    const uint4* __restrict__ rng,
                                                    const int* __restrict__ center_idx,
                                                    float* __restrict__ out){
  __shared__ uint32_t hashv[128*WBLK];            // [slot][thread], private columns (conflict-free)
  const int t = threadIdx.x;
  for(int i=0;i<128;i++) hashv[i*WBLK + t] = 0u;

  const int walk = blockIdx.x*WBLK + t;
  const int b = walk >> 9;
  const float* bx = xyz + (size_t)b*NN*3;
  const int*  br = ring + (size_t)b*NN*3;

  float* out_nb = out;                            // [NWALK][64][3]
  float* out_c  = out + (size_t)NWALK*MM*3;       // [NWALK][3]
  float* out_i  = out_c + (size_t)NWALK*3;        // [NWALK][64] (idx as float)

  const int cidx = center_idx[walk];
  const float cx = bx[3*cidx], cy = bx[3*cidx+1], cz = bx[3*cidx+2];
  out_c[walk*3+0]=cx; out_c[walk*3+1]=cy; out_c[walk*3+2]=cz;
  out_i[(size_t)walk*MM] = (float)cidx;
  { size_t o = (size_t)walk*MM*3; out_nb[o]=0.0f; out_nb[o+1]=0.0f; out_nb[o+2]=0.0f; }

  auto H = [](uint32_t v)->uint32_t { return (v*2654435761u) >> 25; };
  auto slow_has = [&](uint32_t v, uint32_t h)->bool{      // h = first probe (already checked)
    for(;;){ h=(h+1u)&127u; uint32_t c = hashv[h*WBLK+t];
             if (c==0u) return false;
             if (c==v+1u) return true; }
  };
  auto ins = [&](uint32_t v){
    uint32_t h = H(v);
    for(;;){ uint32_t c = hashv[h*WBLK+t];
             if (c==v+1u) return;
             if (c==0u){ hashv[h*WBLK+t]=v+1u; return; }
             h=(h+1u)&127u; }
  };

  ins((uint32_t)cidx);
  int n0 = br[3*cidx], n1 = br[3*cidx+1], n2 = br[3*cidx+2];
  int r00=br[3*n0], r01=br[3*n0+1], r02=br[3*n0+2];
  int r10=br[3*n1], r11=br[3*n1+1], r12=br[3*n1+2];
  int r20=br[3*n2], r21=br[3*n2+1], r22=br[3*n2+2];
  uint4 e = rng[walk];

  for(int i=0;i<STEPS;i++){
    uint4 en = (i < STEPS-1) ? rng[(size_t)(i+1)*NWALK + walk] : e;  // prefetch next rng
    uint32_t h0=H((uint32_t)n0), h1=H((uint32_t)n1), h2=H((uint32_t)n2);
    uint32_t c0=hashv[h0*WBLK+t], c1=hashv[h1*WBLK+t], c2=hashv[h2*WBLK+t];
    bool v0 = (c0!=0u) && ((c0==(uint32_t)n0+1u) || slow_has((uint32_t)n0,h0));
    bool v1 = (c1!=0u) && ((c1==(uint32_t)n1+1u) || slow_has((uint32_t)n1,h1));
    bool v2 = (c2!=0u) && ((c2==(uint32_t)n2+1u) || slow_has((uint32_t)n2,h2));
    bool m0=!v0, m1=!v1, m2=!v2;
    float s0 = m0 ? __fadd_rn(__uint_as_float(e.x), -1.0f) : -1.0f;
    float s1 = m1 ? __fadd_rn(__uint_as_float(e.y), -1.0f) : -1.0f;
    float s2 = m2 ? __fadd_rn(__uint_as_float(e.z), -1.0f) : -1.0f;
    int s = 0; float sb = s0;                     // first-max-wins argmax slot
    if (s1 > sb){ sb=s1; s=1; }
    if (s2 > sb){ sb=s2; s=2; }
    bool any = m0|m1|m2;
    int pick = s==0 ? n0 : (s==1 ? n1 : n2);
    int nxt  = any ? pick : (int)e.w;
    if (any){
      uint32_t cs = s==0?c0:(s==1?c1:c2);
      uint32_t hs = s==0?h0:(s==1?h1:h2);
      if (cs==0u) hashv[hs*WBLK+t] = (uint32_t)nxt + 1u;
      else ins((uint32_t)nxt);                    // collision chain (rare)
    } else {
      ins((uint32_t)nxt);                         // random jump (rare)
    }
    out_i[(size_t)walk*MM + i+1] = (float)nxt;
    float gx=bx[3*nxt], gy=bx[3*nxt+1], gz=bx[3*nxt+2];
    int nn0, nn1, nn2;
    if (any){
      nn0 = s==0?r00:(s==1?r10:r20);
      nn1 = s==0?r01:(s==1?r11:r21);
      nn2 = s==0?r02:(s==1?r12:r22);
    } else {
      nn0 = br[3*nxt]; nn1 = br[3*nxt+1]; nn2 = br[3*nxt+2];   // rare stall
    }
    n0=nn0; n1=nn1; n2=nn2;
    r00=br[3*n0]; r01=br[3*n0+1]; r02=br[3*n0+2];
    r10=br[3*n1]; r11=br[3*n1+1]; r12=br[3*n1+2];
    r20=br[3*n2]; r21=br[3*n2+1]; r22=br[3*n2+2];
    size_t o = ((size_t)walk*MM + (size_t)(i+1))*3;
    out_nb[o]   = __fadd_rn(gx, -cx);
    out_nb[o+1] = __fadd_rn(gy, -cy);
    out_nb[o+2] = __fadd_rn(gz, -cz);
    e = en;
  }
}

// ---------------- launcher ----------------
extern "C" void kernel_launch(void* const* d_in, const int* in_sizes, int n_in,
                              void* d_out, int out_size, void* d_ws, size_t ws_size,
                              hipStream_t stream) {
  const float* xyz  = (const float*)d_in[0];
  const int*   ring = (const int*)d_in[1];

  // workspace layout
  ull*   slots      = (ull*)d_ws;                                 // 2*8*64*8 = 8192 B
  int*   center_idx = (int*)((char*)d_ws + 8192);                 // 4096*4 B
  uint4* rng        = (uint4*)((char*)d_ws + 8192 + 16384);       // 258048*16 B
  float* out        = (float*)d_out;

  hipLaunchKernelGGL(rng_init_kernel, dim3((STEPS*NWALK)/256), dim3(256), 0, stream,
                     rng, slots, center_idx);
  hipLaunchKernelGGL(fps_kernel, dim3(FPS_BLOCKS), dim3(FPT), 0, stream,
                     xyz, slots, center_idx);
  hipLaunchKernelGGL(walk_kernel, dim3(NWALK/WBLK), dim3(WBLK), 0, stream,
                     xyz, ring, rng, center_idx, out);
}